// Round 5
// baseline (1212.369 us; speedup 1.0000x reference)
//
#include <hip/hip_runtime.h>

// 2-layer stacked LSTM: B=256, T=2048, H=64, layer2 hidden=1.
// One block per batch element (256 blocks), 576 threads (9 waves).
//
// Round-4 post-mortem: per-lane register demand (~90) exceeded the 64-VGPR
// allocator budget, so the 64 W1 weights/lane lived in scratch/L2 and were
// re-fetched EVERY step: 65 KB/CU/step (> 32 KB L1) * 2048 * 256 CUs = 34 GB
// of L2 traffic @ ~34.5 TB/s = ~1.0 ms — the observed plateau.
// Fix: split each column's 64-dot across 2 sub-lanes -> 32 weights/lane
// (8 float4), total live ~55 VGPRs: register-resident BY CONSTRUCTION under
// the default 64-VGPR budget. No allocator fight, no pins needed.
//
// Waves 0-7: layer 1. lane l: gate g=l>>4, unit-in-wave uw=(l&15)>>1, sub
//   k=l&1; unit u=8w+uw, column col=g*64+u. Sub k covers W1 rows 32k+1..32k+32.
//   Pair-sum via shfl_xor(1); all 4 gates of a unit in one wave -> gate
//   gather via __shfl; c1/h1 update redundant in the unit's 8 lanes.
// Wave 8: layer 2, 2-stage software pipeline (stage A: butterfly dot for
//   step t-1; stage B: recurrent c2/h2 update for step t-2).
// ONE __syncthreads per step (publishes h1 for the next step).
constexpr int kT = 2048;
constexpr int kB = 256;
constexpr int kH = 64;
constexpr int kThreads = 576;

__device__ __forceinline__ float fast_sig(float x) {
    return __builtin_amdgcn_rcpf(1.0f + __expf(-x));
}
__device__ __forceinline__ float fast_tanh(float x) {
    float t = __expf(2.0f * x);
    return 1.0f - 2.0f * __builtin_amdgcn_rcpf(t + 1.0f);
}

__global__ __launch_bounds__(kThreads) void lstm2_kernel(
    const float* __restrict__ x, const float* __restrict__ W1,
    const float* __restrict__ b1, const float* __restrict__ W2,
    const float* __restrict__ b2, float* __restrict__ out)
{
    __shared__ float x_lds[kT];       // whole input row for this batch elem
    __shared__ float h1_lds[2][kH];   // double-buffered h1

    const int tid = threadIdx.x;
    const int b = blockIdx.x;
    const float* xg = x + (size_t)b * kT;
    float* outg = out + (size_t)b * kT;

    for (int i = tid; i < kT; i += kThreads) x_lds[i] = xg[i];
    if (tid < kH) { h1_lds[0][tid] = 0.0f; h1_lds[1][tid] = 0.0f; }

    const int w = tid >> 6;   // wave id 0..8
    const int l = tid & 63;   // lane

    // ---- layer-1 per-lane state (waves 0-7): 32 weights = 8 float4 ----
    float w0 = 0.0f, b1g = 0.0f;
    float4 wq[8];
    #pragma unroll
    for (int q = 0; q < 8; ++q) wq[q] = make_float4(0.f, 0.f, 0.f, 0.f);
    float c1 = 0.0f;
    int g = 0, k = 0, hoff = 0;

    // ---- layer-2 per-lane state (wave 8) ----
    float w2p0 = 0, w2p1 = 0, w2p2 = 0, w2p3 = 0;
    float4 w2t = {0, 0, 0, 0}, b2v = {0, 0, 0, 0};
    float c2 = 0.0f, h2 = 0.0f;
    float zi_s = 0, zj_s = 0, zf_s = 0, zo_s = 0;

    if (w < 8) {
        g = l >> 4;                    // gate 0..3
        const int uw = (l & 15) >> 1;  // unit-in-wave 0..7
        k = l & 1;                     // sub-lane: rows 32k+1 .. 32k+32
        const int u = 8 * w + uw;
        const int col = g * 64 + u;    // gate-major column
        hoff = 32 * k;
        w0 = W1[col];                  // x weight (added after pair-sum)
        b1g = b1[col];
        #pragma unroll
        for (int q = 0; q < 8; ++q) {
            wq[q].x = W1[(32 * k + 4 * q + 1) * 256 + col];
            wq[q].y = W1[(32 * k + 4 * q + 2) * 256 + col];
            wq[q].z = W1[(32 * k + 4 * q + 3) * 256 + col];
            wq[q].w = W1[(32 * k + 4 * q + 4) * 256 + col];
        }
    } else {
        const int s = l & 15, gg = l >> 4;
        w2p0 = W2[(s +  0) * 4 + gg];
        w2p1 = W2[(s + 16) * 4 + gg];
        w2p2 = W2[(s + 32) * 4 + gg];
        w2p3 = W2[(s + 48) * 4 + gg];
        w2t = ((const float4*)W2)[kH];
        b2v = ((const float4*)b2)[0];
    }
    __syncthreads();

    int cur = 0;
    for (int t = 0; t < kT; ++t) {
        const int nxt = cur ^ 1;
        if (w < 8) {
            // ---- layer-1 step t: partial dot over 32 h values ----
            const float xt = x_lds[t];
            float z0 = 0.f, z1 = 0.f, z2 = 0.f, z3 = 0.f;
            const float4* h4 = (const float4*)(&h1_lds[cur][hoff]);
            #pragma unroll
            for (int q = 0; q < 8; ++q) {
                float4 h = h4[q];   // 2 addr groups/wave: 2-way alias, free
                z0 = fmaf(h.x, wq[q].x, z0);
                z1 = fmaf(h.y, wq[q].y, z1);
                z2 = fmaf(h.z, wq[q].z, z2);
                z3 = fmaf(h.w, wq[q].w, z3);
            }
            float z = (z0 + z1) + (z2 + z3);
            z += __shfl_xor(z, 1);               // pair-sum across sub-lanes
            z += fmaf(xt, w0, b1g);              // x-term + bias (per lane)
            // g==1 -> tanh(z) = 2*sig(2z)-1; g==2 -> sig(z+1); else sig(z)
            float zz = (g == 1) ? 2.0f * z : ((g == 2) ? z + 1.0f : z);
            float sg = fast_sig(zz);
            float a = (g == 1) ? fmaf(2.0f, sg, -1.0f) : sg;
            // gather the 4 gates of this unit (all in this wave)
            const int base = l & 15;
            const float ai = __shfl(a, base);
            const float aj = __shfl(a, base + 16);
            const float af = __shfl(a, base + 32);
            const float ao = __shfl(a, base + 48);
            c1 = fmaf(af, c1, ai * aj);          // redundant in 8 lanes
            const float h1n = ao * fast_tanh(c1);
            if ((l & 0x31) == 0)                 // g==0 && k==0
                h1_lds[nxt][8 * w + (l >> 1)] = h1n;
        } else {
            // ---- stage B: recurrent update for step t-2 (uses staged z) ----
            if (t >= 2) {
                const float zi = zi_s + h2 * w2t.x;
                const float zj = zj_s + h2 * w2t.y;
                const float zf = zf_s + h2 * w2t.z;
                const float zo = zo_s + h2 * w2t.w;
                c2 = fast_sig(zf + 1.0f) * c2 + fast_sig(zi) * fast_tanh(zj);
                h2 = fast_sig(zo) * fast_tanh(c2);
                if (l == 0) outg[t - 2] = h2;
            }
            // ---- stage A: dot products for step t-1 ----
            if (t >= 1) {
                const int s = l & 15;
                const float* hb = h1_lds[cur];
                float p = hb[s] * w2p0;
                p = fmaf(hb[s + 16], w2p1, p);
                p = fmaf(hb[s + 32], w2p2, p);
                p = fmaf(hb[s + 48], w2p3, p);
                p += __shfl_xor(p, 1);
                p += __shfl_xor(p, 2);
                p += __shfl_xor(p, 4);
                p += __shfl_xor(p, 8);
                zi_s = __shfl(p, s)      + b2v.x;
                zj_s = __shfl(p, s + 16) + b2v.y;
                zf_s = __shfl(p, s + 32) + b2v.z;
                zo_s = __shfl(p, s + 48) + b2v.w;
            }
        }
        __syncthreads();
        cur = nxt;
    }

    // ---- epilogue (wave 8): finish steps T-2 and T-1 ----
    if (w == 8) {
        {
            const float zi = zi_s + h2 * w2t.x;
            const float zj = zj_s + h2 * w2t.y;
            const float zf = zf_s + h2 * w2t.z;
            const float zo = zo_s + h2 * w2t.w;
            c2 = fast_sig(zf + 1.0f) * c2 + fast_sig(zi) * fast_tanh(zj);
            h2 = fast_sig(zo) * fast_tanh(c2);
            if (l == 0) outg[kT - 2] = h2;
        }
        {
            const int s = l & 15;
            const float* hb = h1_lds[cur];
            float p = hb[s] * w2p0;
            p = fmaf(hb[s + 16], w2p1, p);
            p = fmaf(hb[s + 32], w2p2, p);
            p = fmaf(hb[s + 48], w2p3, p);
            p += __shfl_xor(p, 1);
            p += __shfl_xor(p, 2);
            p += __shfl_xor(p, 4);
            p += __shfl_xor(p, 8);
            const float zi = __shfl(p, s)      + b2v.x + h2 * w2t.x;
            const float zj = __shfl(p, s + 16) + b2v.y + h2 * w2t.y;
            const float zf = __shfl(p, s + 32) + b2v.z + h2 * w2t.z;
            const float zo = __shfl(p, s + 48) + b2v.w + h2 * w2t.w;
            c2 = fast_sig(zf + 1.0f) * c2 + fast_sig(zi) * fast_tanh(zj);
            h2 = fast_sig(zo) * fast_tanh(c2);
            if (l == 0) outg[kT - 1] = h2;
        }
    }
}

extern "C" void kernel_launch(void* const* d_in, const int* in_sizes, int n_in,
                              void* d_out, int out_size, void* d_ws, size_t ws_size,
                              hipStream_t stream) {
    const float* x  = (const float*)d_in[0];
    const float* W1 = (const float*)d_in[1];
    const float* b1 = (const float*)d_in[2];
    const float* W2 = (const float*)d_in[3];
    const float* b2 = (const float*)d_in[4];
    float* out = (float*)d_out;
    lstm2_kernel<<<kB, kThreads, 0, stream>>>(x, W1, b1, W2, b2, out);
}